// Round 1
// baseline (1467.468 us; speedup 1.0000x reference)
//
#include <hip/hip_runtime.h>

// MPNN on MI355X — fp32 vector-ALU, wave-per-item, readlane-broadcast inner loops.
//
// Algebraic restructure: msg layer-1 is linear before the relu, so
//   m1 = relu(P[dst] + Q[src] + ea@W1e + b1),  P = h@W1[0:64], Q = h@W1[64:128]
// moving 128 of the 134 K-rows from per-edge (800k) to per-node (50k) work.

#define NODES_DIM 64  // EMB

__device__ __forceinline__ float bcast(float v, int lane) {
    return __int_as_float(__builtin_amdgcn_readlane(__float_as_int(v), lane));
}

// h = x @ Win + b   (x: n x 128, Win: 128 x 64)
__global__ __launch_bounds__(256) void k_in(const float* __restrict__ x,
        const float* __restrict__ w, const float* __restrict__ b,
        float* __restrict__ h, int nNodes) {
    const int lane = threadIdx.x & 63;
    const int wid  = blockIdx.x * (blockDim.x >> 6) + (threadIdx.x >> 6);
    const int nw   = gridDim.x * (blockDim.x >> 6);
    float wa[64], wb[64];
#pragma unroll
    for (int k = 0; k < 64; ++k) wa[k] = w[k * 64 + lane];
#pragma unroll
    for (int k = 0; k < 64; ++k) wb[k] = w[(64 + k) * 64 + lane];
    const float bc = b[lane];
    for (int n = wid; n < nNodes; n += nw) {
        float x0 = x[(long)n * 128 + lane];
        float x1 = x[(long)n * 128 + 64 + lane];
        float acc = bc;
#pragma unroll
        for (int k = 0; k < 64; ++k) acc += bcast(x0, k) * wa[k];
#pragma unroll
        for (int k = 0; k < 64; ++k) acc += bcast(x1, k) * wb[k];
        h[(long)n * 64 + lane] = acc;
    }
}

// P = h @ W1[0:64], Q = h @ W1[64:128]   (no bias here)
__global__ __launch_bounds__(256) void k_pre(const float* __restrict__ h,
        const float* __restrict__ w1, float* __restrict__ P, float* __restrict__ Q,
        int nNodes) {
    const int lane = threadIdx.x & 63;
    const int wid  = blockIdx.x * (blockDim.x >> 6) + (threadIdx.x >> 6);
    const int nw   = gridDim.x * (blockDim.x >> 6);
    float wa[64], wb[64];
#pragma unroll
    for (int k = 0; k < 64; ++k) wa[k] = w1[k * 64 + lane];
#pragma unroll
    for (int k = 0; k < 64; ++k) wb[k] = w1[(64 + k) * 64 + lane];
    for (int n = wid; n < nNodes; n += nw) {
        float hv = h[(long)n * 64 + lane];
        float accP = 0.f, accQ = 0.f;
#pragma unroll
        for (int k = 0; k < 64; ++k) {
            float s = bcast(hv, k);
            accP += s * wa[k];
            accQ += s * wb[k];
        }
        P[(long)n * 64 + lane] = accP;
        Q[(long)n * 64 + lane] = accQ;
    }
}

// per-edge: m1 = relu(P[dst]+Q[src]+ea@W1e+b1); m2 = relu(m1@W2+b2); agg[dst] += m2
__global__ __launch_bounds__(256) void k_edge(const float* __restrict__ P,
        const float* __restrict__ Q, const float* __restrict__ ea,
        const int* __restrict__ src, const int* __restrict__ dst,
        const float* __restrict__ w1e, const float* __restrict__ b1,
        const float* __restrict__ w2, const float* __restrict__ b2,
        float* __restrict__ agg, int nEdges) {
    const int lane = threadIdx.x & 63;
    const int wid  = blockIdx.x * (blockDim.x >> 6) + (threadIdx.x >> 6);
    const int nw   = gridDim.x * (blockDim.x >> 6);
    float w2c[64];
#pragma unroll
    for (int k = 0; k < 64; ++k) w2c[k] = w2[k * 64 + lane];
    float w1ec[6];
#pragma unroll
    for (int j = 0; j < 6; ++j) w1ec[j] = w1e[j * 64 + lane];
    const float b1c = b1[lane];
    const float b2c = b2[lane];
    for (int e = wid; e < nEdges; e += nw) {
        const int s = src[e];
        const int d = dst[e];
        float t = P[(long)d * 64 + lane] + Q[(long)s * 64 + lane] + b1c;
#pragma unroll
        for (int j = 0; j < 6; ++j) t += ea[(long)e * 6 + j] * w1ec[j];
        const float m1 = fmaxf(t, 0.f);
        float acc = b2c;
#pragma unroll
        for (int k = 0; k < 64; ++k) acc += bcast(m1, k) * w2c[k];
        const float m2 = fmaxf(acc, 0.f);
        atomicAdd(&agg[(long)d * 64 + lane], m2);
    }
}

// tmp = relu([h, agg] @ U1 + b1)
__global__ __launch_bounds__(256) void k_upd1(const float* __restrict__ h,
        const float* __restrict__ agg, const float* __restrict__ w,
        const float* __restrict__ b, float* __restrict__ tmp, int nNodes) {
    const int lane = threadIdx.x & 63;
    const int wid  = blockIdx.x * (blockDim.x >> 6) + (threadIdx.x >> 6);
    const int nw   = gridDim.x * (blockDim.x >> 6);
    float wa[64], wb[64];
#pragma unroll
    for (int k = 0; k < 64; ++k) wa[k] = w[k * 64 + lane];
#pragma unroll
    for (int k = 0; k < 64; ++k) wb[k] = w[(64 + k) * 64 + lane];
    const float bc = b[lane];
    for (int n = wid; n < nNodes; n += nw) {
        float hv = h[(long)n * 64 + lane];
        float av = agg[(long)n * 64 + lane];
        float acc = bc;
#pragma unroll
        for (int k = 0; k < 64; ++k) acc += bcast(hv, k) * wa[k];
#pragma unroll
        for (int k = 0; k < 64; ++k) acc += bcast(av, k) * wb[k];
        tmp[(long)n * 64 + lane] = fmaxf(acc, 0.f);
    }
}

// h += relu(tmp @ U2 + b2)
__global__ __launch_bounds__(256) void k_upd2(float* __restrict__ h,
        const float* __restrict__ tmp, const float* __restrict__ w,
        const float* __restrict__ b, int nNodes) {
    const int lane = threadIdx.x & 63;
    const int wid  = blockIdx.x * (blockDim.x >> 6) + (threadIdx.x >> 6);
    const int nw   = gridDim.x * (blockDim.x >> 6);
    float w2c[64];
#pragma unroll
    for (int k = 0; k < 64; ++k) w2c[k] = w[k * 64 + lane];
    const float bc = b[lane];
    for (int n = wid; n < nNodes; n += nw) {
        float tv = tmp[(long)n * 64 + lane];
        float acc = bc;
#pragma unroll
        for (int k = 0; k < 64; ++k) acc += bcast(tv, k) * w2c[k];
        h[(long)n * 64 + lane] += fmaxf(acc, 0.f);
    }
}

// colsum[c] += sum_n h[n][c]
__global__ __launch_bounds__(256) void k_colsum(const float* __restrict__ h,
        float* __restrict__ colsum, int nNodes) {
    const int lane = threadIdx.x & 63;
    const int wid  = blockIdx.x * 4 + (threadIdx.x >> 6);
    const int nw   = gridDim.x * 4;
    float s = 0.f;
    for (int n = wid; n < nNodes; n += nw) s += h[(long)n * 64 + lane];
    __shared__ float sm[64];
    if (threadIdx.x < 64) sm[threadIdx.x] = 0.f;
    __syncthreads();
    atomicAdd(&sm[lane], s);
    __syncthreads();
    if (threadIdx.x < 64) atomicAdd(&colsum[threadIdx.x], sm[threadIdx.x]);
}

// out[0] = dot(colsum, pred_w) + nNodes * pred_b
__global__ void k_out(const float* __restrict__ colsum, const float* __restrict__ pw,
                      const float* __restrict__ pb, float* __restrict__ out, int nNodes) {
    const int lane = threadIdx.x;
    float v = colsum[lane] * pw[lane];
#pragma unroll
    for (int off = 32; off; off >>= 1) v += __shfl_down(v, off);
    if (lane == 0) out[0] = v + (float)nNodes * pb[0];
}

extern "C" void kernel_launch(void* const* d_in, const int* in_sizes, int n_in,
                              void* d_out, int out_size, void* d_ws, size_t ws_size,
                              hipStream_t stream) {
    const float* x     = (const float*)d_in[0];
    const int*   ei    = (const int*)d_in[1];
    const float* ea    = (const float*)d_in[2];
    const float* lin_w = (const float*)d_in[3];
    const float* lin_b = (const float*)d_in[4];
    const float* mw1   = (const float*)d_in[5];
    const float* mb1   = (const float*)d_in[6];
    const float* mw2   = (const float*)d_in[7];
    const float* mb2   = (const float*)d_in[8];
    const float* uw1   = (const float*)d_in[9];
    const float* ub1   = (const float*)d_in[10];
    const float* uw2   = (const float*)d_in[11];
    const float* ub2   = (const float*)d_in[12];
    const float* pw    = (const float*)d_in[13];
    const float* pb    = (const float*)d_in[14];

    const int nNodes = in_sizes[0] / 128;
    const int nEdges = in_sizes[1] / 2;
    const int* src = ei;            // edge_index[0]
    const int* dst = ei + nEdges;   // edge_index[1]

    float* h      = (float*)d_ws;
    float* P      = h + (size_t)nNodes * 64;
    float* Q      = P + (size_t)nNodes * 64;
    float* agg    = Q + (size_t)nNodes * 64;
    float* colsum = agg + (size_t)nNodes * 64;

    const int NB_NODE = 1024;
    const int NB_EDGE = 2048;

    k_in<<<NB_NODE, 256, 0, stream>>>(x, lin_w, lin_b, h, nNodes);

    for (int l = 0; l < 4; ++l) {
        const float* w1 = mw1 + (size_t)l * 134 * 64;
        k_pre<<<NB_NODE, 256, 0, stream>>>(h, w1, P, Q, nNodes);
        hipMemsetAsync(agg, 0, (size_t)nNodes * 64 * sizeof(float), stream);
        k_edge<<<NB_EDGE, 256, 0, stream>>>(P, Q, ea, src, dst,
            w1 + 128 * 64, mb1 + l * 64,
            mw2 + (size_t)l * 64 * 64, mb2 + l * 64, agg, nEdges);
        k_upd1<<<NB_NODE, 256, 0, stream>>>(h, agg,
            uw1 + (size_t)l * 128 * 64, ub1 + l * 64, P, nNodes);
        k_upd2<<<NB_NODE, 256, 0, stream>>>(h, P,
            uw2 + (size_t)l * 64 * 64, ub2 + l * 64, nNodes);
    }

    hipMemsetAsync(colsum, 0, 64 * sizeof(float), stream);
    k_colsum<<<512, 256, 0, stream>>>(h, colsum, nNodes);
    k_out<<<1, 64, 0, stream>>>(colsum, pw, pb, (float*)d_out, nNodes);
}